// Round 1
// baseline (823.779 us; speedup 1.0000x reference)
//
#include <hip/hip_runtime.h>

// ---------------------------------------------------------------------------
// PointNet++ set-abstraction block on MI355X.
// B=8, N=4096, K=32, D=64; out [B,N,128] fp32.
// Key ideas:
//  - layer0 is linear in gathered inputs: h0_pre = R[j] - Q[n]
//  - BN training-mode stats via per-block partials + tiny finalize kernels
//  - layers 1/2 as fp16 MFMA (16x16x32) with fp32 accum
//  - max over K commutes with monotone BN affine: store max&min of h2 only
// ws requirement: ~57.2 MB
// ---------------------------------------------------------------------------

using half8  = __attribute__((ext_vector_type(8))) _Float16;
using floatx4 = __attribute__((ext_vector_type(4))) float;

#define NB 8
#define NP 4096
#define NQ (NB*NP)          // 32768 points / queries
#define CNT_INV (1.0f/1048576.0f)   // 1/(B*N*K), exact power of two

// ---- workspace layout (bytes) ----
#define OFF_XYZ4  0ull
#define OFF_Q     (OFF_XYZ4 + (size_t)NQ*4*4)       // xyz4: x,y,z,|x|^2
#define OFF_R     (OFF_Q    + (size_t)NQ*64*4)
#define OFF_IDX   (OFF_R    + (size_t)NQ*64*4)
#define OFF_W1H   (OFF_IDX  + (size_t)NQ*32*4)
#define OFF_W2H   (OFF_W1H  + 4096*2)
#define OFF_P0    (OFF_W2H  + 8192*2)
#define OFF_P1    (OFF_P0   + (size_t)1024*128*4)
#define OFF_P2    (OFF_P1   + (size_t)1024*128*4)
#define OFF_PAR   (OFF_P2   + (size_t)1024*256*4)
#define OFF_MMAX  (OFF_PAR  + 512*4)
#define OFF_MMIN  (OFF_MMAX + (size_t)NQ*128*4)

// ---------------------------------------------------------------------------
// K0: per-point prep: xyz4=(x,y,z,sq), Q = W0_xyz@xyz, R = Q + W0_pts@pts + b0
// one wave per point, lane = output channel. W0 staged in LDS (2-way banks).
// ---------------------------------------------------------------------------
__global__ __launch_bounds__(256) void k_prep(
    const float* __restrict__ xyz, const float* __restrict__ points,
    const float* __restrict__ W0, const float* __restrict__ b0,
    float* __restrict__ xyz4, float* __restrict__ Q, float* __restrict__ R) {
  __shared__ float w0s[64*67];
  for (int i = threadIdx.x; i < 64*67; i += 256) w0s[i] = W0[i];
  __syncthreads();
  int p = blockIdx.x*4 + (threadIdx.x >> 6);
  int o = threadIdx.x & 63;
  float x = xyz[p*3+0], y = xyz[p*3+1], z = xyz[p*3+2];
  const float* wr = w0s + o*67;
  float q = wr[0]*x + wr[1]*y + wr[2]*z;
  float r = b0[o] + q;
  const float* pp = points + (size_t)p*64;
  #pragma unroll 16
  for (int c = 0; c < 64; ++c) r = fmaf(wr[3+c], pp[c], r);
  Q[(size_t)p*64 + o] = q;
  R[(size_t)p*64 + o] = r;
  if (o == 0) {
    float sq = fmaf(x,x, fmaf(y,y, z*z));
    xyz4[p*4+0]=x; xyz4[p*4+1]=y; xyz4[p*4+2]=z; xyz4[p*4+3]=sq;
  }
}

// ---------------------------------------------------------------------------
// K0b: cast W1 (64x64), W2 (128x64) to fp16 row-major [o][c]
// ---------------------------------------------------------------------------
__global__ __launch_bounds__(256) void k_cast(
    const float* __restrict__ W1, const float* __restrict__ W2,
    _Float16* __restrict__ W1h, _Float16* __restrict__ W2h) {
  int t = blockIdx.x*256 + threadIdx.x;
  if (t < 4096) W1h[t] = (_Float16)W1[t];
  if (t < 8192) W2h[t] = (_Float16)W2[t];
}

// ---------------------------------------------------------------------------
// K1: exact kNN (32 smallest squared dists, ties -> lower index).
// One wave per query; sorted list in lanes 0..31; ballot fast path.
// dist formula identical to reference: sq_n + sq_j - 2*dot.
// ---------------------------------------------------------------------------
__global__ __launch_bounds__(256) void k_knn(
    const float* __restrict__ xyz4, int* __restrict__ idxb) {
  __shared__ float4 tile[64];
  int wg = threadIdx.x >> 6, lane = threadIdx.x & 63;
  int qid = blockIdx.x*4 + wg;
  int b = qid >> 12;
  const float4* xb = (const float4*)xyz4 + (size_t)b*NP;
  float4 me = xb[qid & 4095];

  unsigned ku = 0xFFFFFFFFu;   // sorted dist-bit keys, lanes 0..31 ascending
  int jv = 0;
  unsigned thr = 0xFFFFFFFFu;  // current 32nd-smallest key (wave uniform)

  for (int c = 0; c < 64; ++c) {
    __syncthreads();
    if (threadIdx.x < 64) tile[threadIdx.x] = xb[c*64 + threadIdx.x];
    __syncthreads();
    float4 cd = tile[lane];
    int j = c*64 + lane;
    float dot = fmaf(me.x, cd.x, fmaf(me.y, cd.y, me.z*cd.z));
    float d = fmaf(-2.0f, dot, me.w + cd.w);
    unsigned u = __float_as_uint(d);
    u ^= ((unsigned)((int)u >> 31)) | 0x80000000u;   // monotone map
    unsigned long long ball = __ballot(u < thr);
    while (ball) {
      int src = __ffsll(ball) - 1;
      ball &= ball - 1;
      unsigned cu = __shfl(u, src);
      int cj = __shfl(j, src);
      if (cu < thr) {   // recheck: thr may have tightened
        unsigned long long m = __ballot(lane < 32 && ku < cu);
        int pos = __popcll(m);
        unsigned ku_up = __shfl_up(ku, 1);
        int jv_up = __shfl_up(jv, 1);
        if (lane < 32) {
          if (lane > pos)      { ku = ku_up; jv = jv_up; }
          else if (lane == pos){ ku = cu;    jv = cj;    }
        }
        thr = __shfl(ku, 31);
      }
    }
  }
  if (lane < 32) idxb[(size_t)qid*32 + lane] = jv;
}

// ---------------------------------------------------------------------------
// K2: stats of h0_pre = R[j] - Q[n].  1024 blocks x 32 queries.
// partial (sum,sumsq)[64] per block -> p0[block][128]
// ---------------------------------------------------------------------------
__global__ __launch_bounds__(256) void k_stats0(
    const float* __restrict__ R, const float* __restrict__ Q,
    const int* __restrict__ idxb, float* __restrict__ p0) {
  int o = threadIdx.x & 63, wg = threadIdx.x >> 6;
  float s = 0.f, ss = 0.f;
  for (int qi = 0; qi < 8; ++qi) {
    int qid = blockIdx.x*32 + wg*8 + qi;
    const float* Rb = R + (size_t)(qid & ~4095)*64;
    float qv = Q[(size_t)qid*64 + o];
    const int* ix = idxb + (size_t)qid*32;
    #pragma unroll 8
    for (int k = 0; k < 32; ++k) {
      float v = Rb[(size_t)ix[k]*64 + o] - qv;
      s += v; ss = fmaf(v, v, ss);
    }
  }
  __shared__ float red[512];
  red[threadIdx.x] = s; red[256 + threadIdx.x] = ss;
  __syncthreads();
  if (threadIdx.x < 64) {
    float S  = red[o] + red[64+o] + red[128+o] + red[192+o];
    float SS = red[256+o] + red[320+o] + red[384+o] + red[448+o];
    p0[blockIdx.x*128 + o]      = S;
    p0[blockIdx.x*128 + 64 + o] = SS;
  }
}

// ---------------------------------------------------------------------------
// K3: finalize BN stats -> affine params (scale, shift) at par[poff..]
// ---------------------------------------------------------------------------
__global__ void k_fin(const float* __restrict__ part, int C,
                      const float* __restrict__ g, const float* __restrict__ beta,
                      float* __restrict__ par, int poff) {
  int o = threadIdx.x;
  float S = 0.f, SS = 0.f;
  for (int s = 0; s < 1024; ++s) {
    S  += part[s*2*C + o];
    SS += part[s*2*C + C + o];
  }
  float mu  = S * CNT_INV;
  float var = SS * CNT_INV - mu*mu;
  float sc  = g[o] * rsqrtf(var + 1e-5f);
  par[poff + o]     = sc;
  par[poff + C + o] = beta[o] - mu*sc;
}

// ---------------------------------------------------------------------------
// K4: layer1 via fp16 MFMA; emit stats1 partials. 1024 blocks x 8 groups
// (group = 4 queries = 128 rows). Wave w owns output cols 16w..16w+15.
// ---------------------------------------------------------------------------
__global__ __launch_bounds__(256) void k_l1(
    const float* __restrict__ R, const float* __restrict__ Q,
    const int* __restrict__ idxb, const _Float16* __restrict__ W1h,
    const float* __restrict__ b1, const float* __restrict__ par,
    float* __restrict__ p1) {
  __shared__ __align__(16) _Float16 x1[128*72];
  int o = threadIdx.x & 63, wg = threadIdx.x >> 6;
  int m16 = o & 15, quad = o >> 4;
  float sc0 = par[o], sh0 = par[64 + o];
  int col = wg*16 + m16;
  half8 bf0 = *(const half8*)(W1h + col*64 + quad*8);
  half8 bf1 = *(const half8*)(W1h + col*64 + 32 + quad*8);
  float b1c = b1[col];
  float s = 0.f, ss = 0.f;

  for (int gi = 0; gi < 8; ++gi) {
    int q0 = (blockIdx.x*8 + gi) * 4;
    { // phase A: build x1 tile (fp16) = relu(affine0(R[j]-Q[n]))
      int qid = q0 + wg;
      const float* Rb = R + (size_t)(qid & ~4095)*64;
      float qv = Q[(size_t)qid*64 + o];
      const int* ix = idxb + (size_t)qid*32;
      #pragma unroll 4
      for (int r = 0; r < 32; ++r) {
        float v = fmaf(Rb[(size_t)ix[r]*64 + o] - qv, sc0, sh0);
        x1[(wg*32 + r)*72 + o] = (_Float16)fmaxf(v, 0.f);
      }
    }
    __syncthreads();
    // phase B: 8 row-tiles x (K=64 as 2 chunks)
    #pragma unroll
    for (int rt = 0; rt < 8; ++rt) {
      const _Float16* ap = x1 + (rt*16 + m16)*72 + quad*8;
      half8 a0 = *(const half8*)(ap);
      half8 a1 = *(const half8*)(ap + 32);
      floatx4 acc = {0.f,0.f,0.f,0.f};
      acc = __builtin_amdgcn_mfma_f32_16x16x32_f16(a0, bf0, acc, 0,0,0);
      acc = __builtin_amdgcn_mfma_f32_16x16x32_f16(a1, bf1, acc, 0,0,0);
      #pragma unroll
      for (int rg = 0; rg < 4; ++rg) {
        float h = acc[rg] + b1c;
        s += h; ss = fmaf(h, h, ss);
      }
    }
    __syncthreads();
  }
  s  += __shfl_xor(s, 16);  s  += __shfl_xor(s, 32);
  ss += __shfl_xor(ss, 16); ss += __shfl_xor(ss, 32);
  if (quad == 0) {
    p1[blockIdx.x*128 + col]      = s;
    p1[blockIdx.x*128 + 64 + col] = ss;
  }
}

// ---------------------------------------------------------------------------
// K6: layer1 (recompute) -> bn1+relu -> layer2 MFMA -> stats2 partials +
// per-query max/min over K of h2 (pre-BN).  Wave w: l1 cols 16w..16w+15,
// l2 col-tiles {w, w+4}.
// ---------------------------------------------------------------------------
__global__ __launch_bounds__(256) void k_l2(
    const float* __restrict__ R, const float* __restrict__ Q,
    const int* __restrict__ idxb, const _Float16* __restrict__ W1h,
    const _Float16* __restrict__ W2h, const float* __restrict__ b1,
    const float* __restrict__ b2, const float* __restrict__ par,
    float* __restrict__ p2, float* __restrict__ Mmax, float* __restrict__ Mmin) {
  __shared__ __align__(16) _Float16 x1[128*72];
  __shared__ __align__(16) _Float16 x2[128*72];
  int o = threadIdx.x & 63, wg = threadIdx.x >> 6;
  int m16 = o & 15, quad = o >> 4;
  float sc0 = par[o], sh0 = par[64 + o];
  int col1 = wg*16 + m16;
  float sc1 = par[128 + col1], sh1 = par[192 + col1];
  half8 b1f0 = *(const half8*)(W1h + col1*64 + quad*8);
  half8 b1f1 = *(const half8*)(W1h + col1*64 + 32 + quad*8);
  float b1c = b1[col1];
  int colA = wg*16 + m16, colB = 64 + wg*16 + m16;
  half8 b2A0 = *(const half8*)(W2h + colA*64 + quad*8);
  half8 b2A1 = *(const half8*)(W2h + colA*64 + 32 + quad*8);
  half8 b2B0 = *(const half8*)(W2h + colB*64 + quad*8);
  half8 b2B1 = *(const half8*)(W2h + colB*64 + 32 + quad*8);
  float b2a = b2[colA], b2b = b2[colB];
  float sA=0.f, ssA=0.f, sB=0.f, ssB=0.f;

  for (int gi = 0; gi < 8; ++gi) {
    int q0 = (blockIdx.x*8 + gi) * 4;
    { // phase A
      int qid = q0 + wg;
      const float* Rb = R + (size_t)(qid & ~4095)*64;
      float qv = Q[(size_t)qid*64 + o];
      const int* ix = idxb + (size_t)qid*32;
      #pragma unroll 4
      for (int r = 0; r < 32; ++r) {
        float v = fmaf(Rb[(size_t)ix[r]*64 + o] - qv, sc0, sh0);
        x1[(wg*32 + r)*72 + o] = (_Float16)fmaxf(v, 0.f);
      }
    }
    __syncthreads();
    // phase B: layer1 -> x2 = relu(affine1(h1)), fp16
    #pragma unroll
    for (int rt = 0; rt < 8; ++rt) {
      const _Float16* ap = x1 + (rt*16 + m16)*72 + quad*8;
      half8 a0 = *(const half8*)(ap);
      half8 a1 = *(const half8*)(ap + 32);
      floatx4 acc = {0.f,0.f,0.f,0.f};
      acc = __builtin_amdgcn_mfma_f32_16x16x32_f16(a0, b1f0, acc, 0,0,0);
      acc = __builtin_amdgcn_mfma_f32_16x16x32_f16(a1, b1f1, acc, 0,0,0);
      #pragma unroll
      for (int rg = 0; rg < 4; ++rg) {
        float h = acc[rg] + b1c;
        float v = fmaxf(fmaf(h, sc1, sh1), 0.f);
        x2[(rt*16 + quad*4 + rg)*72 + col1] = (_Float16)v;
      }
    }
    __syncthreads();
    // phase C: layer2, 2 col-tiles; stats + per-query max/min
    float mxA=0.f, mnA=0.f, mxB=0.f, mnB=0.f;
    #pragma unroll
    for (int rt = 0; rt < 8; ++rt) {
      const _Float16* ap = x2 + (rt*16 + m16)*72 + quad*8;
      half8 a0 = *(const half8*)(ap);
      half8 a1 = *(const half8*)(ap + 32);
      floatx4 accA = {0.f,0.f,0.f,0.f}, accB = {0.f,0.f,0.f,0.f};
      accA = __builtin_amdgcn_mfma_f32_16x16x32_f16(a0, b2A0, accA, 0,0,0);
      accA = __builtin_amdgcn_mfma_f32_16x16x32_f16(a1, b2A1, accA, 0,0,0);
      accB = __builtin_amdgcn_mfma_f32_16x16x32_f16(a0, b2B0, accB, 0,0,0);
      accB = __builtin_amdgcn_mfma_f32_16x16x32_f16(a1, b2B1, accB, 0,0,0);
      float hA0 = accA[0]+b2a, hA1 = accA[1]+b2a, hA2 = accA[2]+b2a, hA3 = accA[3]+b2a;
      float hB0 = accB[0]+b2b, hB1 = accB[1]+b2b, hB2 = accB[2]+b2b, hB3 = accB[3]+b2b;
      sA += hA0+hA1+hA2+hA3;
      ssA = fmaf(hA0,hA0, fmaf(hA1,hA1, fmaf(hA2,hA2, fmaf(hA3,hA3, ssA))));
      sB += hB0+hB1+hB2+hB3;
      ssB = fmaf(hB0,hB0, fmaf(hB1,hB1, fmaf(hB2,hB2, fmaf(hB3,hB3, ssB))));
      float m4A = fmaxf(fmaxf(hA0,hA1), fmaxf(hA2,hA3));
      float n4A = fminf(fminf(hA0,hA1), fminf(hA2,hA3));
      float m4B = fmaxf(fmaxf(hB0,hB1), fmaxf(hB2,hB3));
      float n4B = fminf(fminf(hB0,hB1), fminf(hB2,hB3));
      if ((rt & 1) == 0) { mxA=m4A; mnA=n4A; mxB=m4B; mnB=n4B; }
      else {
        mxA=fmaxf(mxA,m4A); mnA=fminf(mnA,n4A);
        mxB=fmaxf(mxB,m4B); mnB=fminf(mnB,n4B);
        // combine the 4 quads (rows) of this query
        mxA=fmaxf(mxA,__shfl_xor(mxA,16)); mxA=fmaxf(mxA,__shfl_xor(mxA,32));
        mnA=fminf(mnA,__shfl_xor(mnA,16)); mnA=fminf(mnA,__shfl_xor(mnA,32));
        mxB=fmaxf(mxB,__shfl_xor(mxB,16)); mxB=fmaxf(mxB,__shfl_xor(mxB,32));
        mnB=fminf(mnB,__shfl_xor(mnB,16)); mnB=fminf(mnB,__shfl_xor(mnB,32));
        if (quad == 0) {
          int qid = q0 + (rt >> 1);
          Mmax[(size_t)qid*128 + colA] = mxA;  Mmin[(size_t)qid*128 + colA] = mnA;
          Mmax[(size_t)qid*128 + colB] = mxB;  Mmin[(size_t)qid*128 + colB] = mnB;
        }
      }
    }
    __syncthreads();
  }
  sA += __shfl_xor(sA,16); sA += __shfl_xor(sA,32);
  ssA += __shfl_xor(ssA,16); ssA += __shfl_xor(ssA,32);
  sB += __shfl_xor(sB,16); sB += __shfl_xor(sB,32);
  ssB += __shfl_xor(ssB,16); ssB += __shfl_xor(ssB,32);
  if (quad == 0) {
    p2[blockIdx.x*256 + colA]        = sA;
    p2[blockIdx.x*256 + 128 + colA]  = ssA;
    p2[blockIdx.x*256 + colB]        = sB;
    p2[blockIdx.x*256 + 128 + colB]  = ssB;
  }
}

// ---------------------------------------------------------------------------
// K7: out = relu(affine2(max-or-min)).  affine monotone: g>=0 -> max.
// ---------------------------------------------------------------------------
__global__ __launch_bounds__(256) void k_out(
    const float* __restrict__ Mmax, const float* __restrict__ Mmin,
    const float* __restrict__ par, float* __restrict__ out) {
  size_t e = (size_t)blockIdx.x*256 + threadIdx.x;
  int col = (int)(e & 127);
  float sc = par[256 + col], sh = par[384 + col];
  float m = (sc >= 0.f) ? Mmax[e] : Mmin[e];
  out[e] = fmaxf(fmaf(m, sc, sh), 0.f);
}

// ---------------------------------------------------------------------------
extern "C" void kernel_launch(void* const* d_in, const int* in_sizes, int n_in,
                              void* d_out, int out_size, void* d_ws, size_t ws_size,
                              hipStream_t stream) {
  const float* xyz    = (const float*)d_in[0];
  const float* points = (const float*)d_in[1];
  const float* W0     = (const float*)d_in[2];
  const float* b0     = (const float*)d_in[3];
  const float* g0     = (const float*)d_in[4];
  const float* beta0  = (const float*)d_in[5];
  const float* W1     = (const float*)d_in[6];
  const float* b1     = (const float*)d_in[7];
  const float* g1     = (const float*)d_in[8];
  const float* beta1  = (const float*)d_in[9];
  const float* W2     = (const float*)d_in[10];
  const float* b2     = (const float*)d_in[11];
  const float* g2     = (const float*)d_in[12];
  const float* beta2  = (const float*)d_in[13];
  // d_in[14] = nsample (=32, hardcoded as K)

  char* ws = (char*)d_ws;
  float*     xyz4 = (float*)(ws + OFF_XYZ4);
  float*     Qb   = (float*)(ws + OFF_Q);
  float*     Rb   = (float*)(ws + OFF_R);
  int*       idxb = (int*)  (ws + OFF_IDX);
  _Float16*  W1h  = (_Float16*)(ws + OFF_W1H);
  _Float16*  W2h  = (_Float16*)(ws + OFF_W2H);
  float*     p0   = (float*)(ws + OFF_P0);
  float*     p1   = (float*)(ws + OFF_P1);
  float*     p2   = (float*)(ws + OFF_P2);
  float*     par  = (float*)(ws + OFF_PAR);
  float*     Mmax = (float*)(ws + OFF_MMAX);
  float*     Mmin = (float*)(ws + OFF_MMIN);
  float*     out  = (float*)d_out;

  hipLaunchKernelGGL(k_prep,  dim3(NQ/4), dim3(256), 0, stream, xyz, points, W0, b0, xyz4, Qb, Rb);
  hipLaunchKernelGGL(k_cast,  dim3(32),   dim3(256), 0, stream, W1, W2, W1h, W2h);
  hipLaunchKernelGGL(k_knn,   dim3(NQ/4), dim3(256), 0, stream, xyz4, idxb);
  hipLaunchKernelGGL(k_stats0,dim3(1024), dim3(256), 0, stream, Rb, Qb, idxb, p0);
  hipLaunchKernelGGL(k_fin,   dim3(1),    dim3(64),  0, stream, p0, 64, g0, beta0, par, 0);
  hipLaunchKernelGGL(k_l1,    dim3(1024), dim3(256), 0, stream, Rb, Qb, idxb, W1h, b1, par, p1);
  hipLaunchKernelGGL(k_fin,   dim3(1),    dim3(64),  0, stream, p1, 64, g1, beta1, par, 128);
  hipLaunchKernelGGL(k_l2,    dim3(1024), dim3(256), 0, stream, Rb, Qb, idxb, W1h, W2h, b1, b2, par, p2, Mmax, Mmin);
  hipLaunchKernelGGL(k_fin,   dim3(1),    dim3(128), 0, stream, p2, 128, g2, beta2, par, 256);
  hipLaunchKernelGGL(k_out,   dim3(out_size/256), dim3(256), 0, stream, Mmax, Mmin, par, out);
}